// Round 9
// baseline (133.402 us; speedup 1.0000x reference)
//
#include <hip/hip_runtime.h>
#include <math.h>

// dims
#define HWHW 2304   // 48*48
#define JD   144    // 12*12
#define LSP  148    // Ls row stride in dwords

typedef __attribute__((ext_vector_type(8))) short short8;
typedef __attribute__((ext_vector_type(4))) float f32x4;
typedef __attribute__((ext_vector_type(2))) float f32x2;

__device__ inline ushort f2bf(float f) {
  uint u = __float_as_uint(f);
  u += 0x7fffu + ((u >> 16) & 1u);   // RNE
  return (ushort)(u >> 16);
}
__device__ inline float bf2f(ushort s) { return __uint_as_float((uint)s << 16); }
__device__ inline uint packbf(float hi, float lo) {   // truncating {hi16(hi),hi16(lo)}
  return __builtin_amdgcn_perm(__float_as_uint(hi), __float_as_uint(lo), 0x07060302);
}

// ws layout (byte offsets)
// vn0     [8][144] f32       @ 0
// vn1     [8][144] f32       @ 4608
// kt_bf   [8][144][32] u16   @ 9216    (73728 B)
// vtT_bf  [8][32][160] u16   @ 82944   (81920 B, j=144..159 zeroed)
// outh_bf [2][2304][128] u16 @ 164864  (1179648 B, end 1344512 B)

// grid (12 hd, 8 bg), 384 thr = 6 waves. Fused: q=Wq·x via MFMA (wave w owns
// conv input row ry=w) -> depthwise conv -> GELU -> proj -> tanh -> grid coords
// -> bilinear sample -> k/v proj (bf16 out).
__global__ __launch_bounds__(384) void offset_kv_kernel(
    const float* __restrict__ x, const float* __restrict__ wq,
    const float* __restrict__ wdw, const float* __restrict__ bdw,
    const float* __restrict__ wproj, const float* __restrict__ wk,
    const float* __restrict__ wv,
    float* __restrict__ vn0, float* __restrict__ vn1,
    ushort* __restrict__ ktb, ushort* __restrict__ vtb) {
  __shared__ float qs[288][33];      // [ry*48+col][c], +1 pad
  __shared__ float wdws[36][32];     // [k][c]
  __shared__ float wkl[32][33], wvl[32][33];   // [d][c]
  __shared__ float kvs[32][13];      // [c][j] (+pad)
  __shared__ float spx[12], spy[12];
  int hd = blockIdx.x, bg = blockIdx.y, b = bg >> 2, g = bg & 3;
  int t = threadIdx.x;
  int w = t >> 6, lane = t & 63, lam = lane & 15, quad = lane >> 4;

  // ---- q-tile via MFMA: wave w computes conv-input row ry=w (hy=hd*4-1+w) ----
  {
    int hy = hd * 4 - 1 + w;
    if (hy >= 0 && hy < 48) {
      // B-frags of Wq^T (shared by the wave's 3 tiles)
      const float* wqg = wq + (g * 32) * 32;
      float4 wa = *(const float4*)(wqg + lam * 32 + quad * 8);
      float4 wb = *(const float4*)(wqg + lam * 32 + quad * 8 + 4);
      float4 wc = *(const float4*)(wqg + (16 + lam) * 32 + quad * 8);
      float4 wd = *(const float4*)(wqg + (16 + lam) * 32 + quad * 8 + 4);
      union { uint u[4]; short8 s8; } bf0, bf1;
      bf0.u[0] = packbf(wa.y, wa.x); bf0.u[1] = packbf(wa.w, wa.z);
      bf0.u[2] = packbf(wb.y, wb.x); bf0.u[3] = packbf(wb.w, wb.z);
      bf1.u[0] = packbf(wc.y, wc.x); bf1.u[1] = packbf(wc.w, wc.z);
      bf1.u[2] = packbf(wd.y, wd.x); bf1.u[3] = packbf(wd.w, wd.z);
      const float* xg = x + (b * 128 + g * 32) * HWHW + hy * 48;
#pragma unroll
      for (int tt = 0; tt < 3; ++tt) {
        int col = tt * 16 + lam;
        union { uint u[4]; short8 s8; } xa;
#pragma unroll
        for (int j = 0; j < 4; ++j) {
          float x0 = xg[(quad * 8 + 2 * j) * HWHW + col];
          float x1 = xg[(quad * 8 + 2 * j + 1) * HWHW + col];
          xa.u[j] = packbf(x1, x0);
        }
        f32x4 z = {0.f, 0.f, 0.f, 0.f};
        f32x4 d0 = __builtin_amdgcn_mfma_f32_16x16x32_bf16(xa.s8, bf0.s8, z, 0, 0, 0);
        f32x4 d1 = __builtin_amdgcn_mfma_f32_16x16x32_bf16(xa.s8, bf1.s8, z, 0, 0, 0);
        int p = w * 48 + tt * 16 + quad * 4;
#pragma unroll
        for (int r = 0; r < 4; ++r) {
          qs[p + r][lam] = d0[r];
          qs[p + r][16 + lam] = d1[r];
        }
      }
    } else {
#pragma unroll
      for (int tt = 0; tt < 3; ++tt) {
        int p = w * 48 + tt * 16 + quad * 4;
#pragma unroll
        for (int r = 0; r < 4; ++r) {
          qs[p + r][lam] = 0.f;
          qs[p + r][16 + lam] = 0.f;
        }
      }
    }
  }
  for (int u = t; u < 1152; u += 384) wdws[u >> 5][u & 31] = wdw[(u & 31) * 36 + (u >> 5)];
  for (int u = t; u < 1024; u += 384) {
    int d = u >> 5, c = u & 31;
    wkl[d][c] = wk[g * 1024 + u];
    wvl[d][c] = wv[g * 1024 + u];
  }
  __syncthreads();
  {
    int wd = t >> 5, c = t & 31;
    float s = 0.f;
#pragma unroll
    for (int ky = 0; ky < 6; ++ky) {
#pragma unroll
      for (int kx = 0; kx < 6; ++kx) {
        int wx = wd * 4 - 1 + kx;
        if (wx >= 0 && wx < 48)
          s += wdws[ky * 6 + kx][c] * qs[ky * 48 + wx][c];
      }
    }
    s += bdw[c];
    s = 0.5f * s * (1.f + erff(s * 0.70710678118654752f));  // exact GELU
    float g0 = wproj[c] * s;
    float g1 = wproj[32 + c] * s;
#pragma unroll
    for (int k = 16; k >= 1; k >>= 1) {
      g0 += __shfl_xor(g0, k, 64);
      g1 += __shfl_xor(g1, k, 64);
    }
    if (c == 0) {
      float off0 = tanhf(g0) * 4.f;
      float off1 = tanhf(g1) * 4.f;
      float n0 = 2.f * ((float)wd + off0) / 11.f - 1.f;
      float n1 = 2.f * ((float)hd + off1) / 11.f - 1.f;
      int idx = bg * JD + hd * 12 + wd;
      vn0[idx] = n0;
      vn1[idx] = n1;
      spx[wd] = ((n0 + 1.f) * 48.f - 1.f) * 0.5f;
      spy[wd] = ((n1 + 1.f) * 48.f - 1.f) * 0.5f;
    }
  }
  __syncthreads();
  {
    int j = t >> 5, c = t & 31;
    float fx = spx[j], fy = spy[j];
    float x0 = floorf(fx), y0 = floorf(fy);
    float wx = fx - x0, wy = fy - y0;
    int xi = (int)x0, yi = (int)y0;
    const float* xp = x + (b * 128 + g * 32 + c) * HWHW;
    float v00 = 0.f, v10 = 0.f, v01 = 0.f, v11 = 0.f;
    bool okx0 = (xi >= 0) & (xi < 48), okx1 = (xi + 1 >= 0) & (xi + 1 < 48);
    if (yi >= 0 && yi < 48) {
      if (okx0) v00 = xp[yi * 48 + xi];
      if (okx1) v10 = xp[yi * 48 + xi + 1];
    }
    if (yi + 1 >= 0 && yi + 1 < 48) {
      if (okx0) v01 = xp[(yi + 1) * 48 + xi];
      if (okx1) v11 = xp[(yi + 1) * 48 + xi + 1];
    }
    kvs[c][j] = v00 * (1.f - wx) * (1.f - wy) + v10 * wx * (1.f - wy)
              + v01 * (1.f - wx) * wy + v11 * wx * wy;
  }
  __syncthreads();
  {
    int j = t >> 5, d = t & 31;
    float ak = 0.f, av = 0.f;
#pragma unroll
    for (int c = 0; c < 32; ++c) {
      float val = kvs[c][j];
      ak += wkl[d][c] * val;
      av += wvl[d][c] * val;
    }
    int jg = hd * 12 + j;
    ktb[bg * 4608 + jg * 32 + d] = f2bf(ak);
    vtb[bg * 5120 + d * 160 + jg] = f2bf(av);
  }
  if (hd == 0) {   // zero the v K-pad for this bg (j = 144..159)
    for (int u = t; u < 512; u += 384)
      vtb[bg * 5120 + (u >> 4) * 160 + 144 + (u & 15)] = 0;
  }
}

// Fused attention: block = (bg, 16 q-rows), 256 thr = 4 waves.
// q computed inline via MFMA from x/wq; k/v straight from global; P2 bias MLP
// on MFMA with packed-f32 (v_pk_fma_f32) h-build and epilogue.
__global__ __launch_bounds__(256) void attn_fused_kernel(
    const float* __restrict__ x, const float* __restrict__ wq,
    const ushort* __restrict__ ktb, const ushort* __restrict__ vtb,
    const float* __restrict__ vn0, const float* __restrict__ vn1,
    const float* __restrict__ w0, const float* __restrict__ b0,
    const float* __restrict__ w1, const float* __restrict__ b1,
    const float* __restrict__ w2, const float* __restrict__ b2,
    ushort* __restrict__ outh) {
  __shared__ __align__(16) char smem[11648];
  float* Ls = (float*)smem;                    // [16][LSP] fp32; P bf16 at dwords 64..143
  ushort* qbf = (ushort*)(smem + 9472);        // [16][32] bf16
  float* sv0 = (float*)(smem + 10496);         // [144]
  float* sv1 = (float*)(smem + 11072);         // [144]

  int bg = blockIdx.y, b = bg >> 2, g = bg & 3;
  int i0 = blockIdx.x * 16;
  int t = threadIdx.x;
  int w = t >> 6, lane = t & 63;
  int lam = lane & 15, quad = lane >> 4;

  if (t < JD) { sv0[t] = vn0[bg * JD + t]; sv1[t] = vn1[bg * JD + t]; }

  // ---- q-tile via MFMA: D = X[16 rows][32c] · Wq^T -> C-layout -> LDS ----
  {
    const float* wqg = wq + (g * 32) * 32;
    float4 wa = *(const float4*)(wqg + lam * 32 + quad * 8);
    float4 wb = *(const float4*)(wqg + lam * 32 + quad * 8 + 4);
    float4 wc = *(const float4*)(wqg + (16 + lam) * 32 + quad * 8);
    float4 wd = *(const float4*)(wqg + (16 + lam) * 32 + quad * 8 + 4);
    union { uint u[4]; short8 s8; } bf0, bf1, xa;
    bf0.u[0] = packbf(wa.y, wa.x); bf0.u[1] = packbf(wa.w, wa.z);
    bf0.u[2] = packbf(wb.y, wb.x); bf0.u[3] = packbf(wb.w, wb.z);
    bf1.u[0] = packbf(wc.y, wc.x); bf1.u[1] = packbf(wc.w, wc.z);
    bf1.u[2] = packbf(wd.y, wd.x); bf1.u[3] = packbf(wd.w, wd.z);
    const float* xg = x + (b * 128 + g * 32) * HWHW + i0;
#pragma unroll
    for (int j = 0; j < 4; ++j) {
      float x0 = xg[(quad * 8 + 2 * j) * HWHW + lam];
      float x1 = xg[(quad * 8 + 2 * j + 1) * HWHW + lam];
      xa.u[j] = packbf(x1, x0);
    }
    f32x4 z = {0.f, 0.f, 0.f, 0.f};
    f32x4 d0 = __builtin_amdgcn_mfma_f32_16x16x32_bf16(xa.s8, bf0.s8, z, 0, 0, 0);
    f32x4 d1 = __builtin_amdgcn_mfma_f32_16x16x32_bf16(xa.s8, bf1.s8, z, 0, 0, 0);
#pragma unroll
    for (int r = 0; r < 4; ++r) {
      qbf[(quad * 4 + r) * 32 + lam] = f2bf(d0[r]);
      qbf[(quad * 4 + r) * 32 + 16 + lam] = f2bf(d1[r]);
    }
  }

  // ---- per-lane resident weights (float2-packed for v_pk_fma_f32) ----
  f32x2 w00r2[4], w01r2[4], b0r2[4];
#pragma unroll
  for (int j = 0; j < 4; ++j) {
    int k = quad * 8 + 2 * j;
    w00r2[j] = (f32x2){w0[k], w0[k + 1]};
    w01r2[j] = (f32x2){w0[32 + k], w0[32 + k + 1]};
    b0r2[j]  = (f32x2){b0[k], b0[k + 1]};
  }
  short8 w1f0, w1f1;   // W1^T A-frags (m=n-out, k=c-in), two 16-row tiles
#pragma unroll
  for (int j = 0; j < 8; ++j) {
    int k = quad * 8 + j;
    w1f0[j] = (short)f2bf(w1[k * 32 + lam]);
    w1f1[j] = (short)f2bf(w1[k * 32 + 16 + lam]);
  }
  f32x4 zA, zB;       // b1 folded into C-init (n = quad*4+r / 16+quad*4+r)
  f32x2 w2A01, w2A23, w2B01, w2B23;
#pragma unroll
  for (int r = 0; r < 4; ++r) {
    zA[r] = b1[quad * 4 + r];
    zB[r] = b1[16 + quad * 4 + r];
  }
  w2A01 = (f32x2){w2[quad * 4], w2[quad * 4 + 1]};
  w2A23 = (f32x2){w2[quad * 4 + 2], w2[quad * 4 + 3]};
  w2B01 = (f32x2){w2[16 + quad * 4], w2[16 + quad * 4 + 1]};
  w2B23 = (f32x2){w2[16 + quad * 4 + 2], w2[16 + quad * 4 + 3]};
  float b2s = b2[0];

  // ---- prefetch v-frags for P4 (waves 0,1) ----
  short8 vf[5];
  if (w < 2) {
    const ushort* vb = vtb + bg * 5120 + (w * 16 + lam) * 160;
#pragma unroll
    for (int kb = 0; kb < 5; ++kb)
      vf[kb] = *(const short8*)(vb + kb * 32 + quad * 8);
  }

  __syncthreads();   // B0: qbf + sv ready

  // ---- P1: sim = q·kT (scaled); k straight from global ----
  const float scale = 0.17677669529663687f;   // 32^-0.5
  {
    short8 aq = *(const short8*)(qbf + lam * 32 + quad * 8);
    const ushort* kb = ktb + bg * 4608;
#pragma unroll 1
    for (int jt = w; jt < 9; jt += 4) {
      short8 bk = *(const short8*)(kb + (jt * 16 + lam) * 32 + quad * 8);
      f32x4 acc = {0.f, 0.f, 0.f, 0.f};
      acc = __builtin_amdgcn_mfma_f32_16x16x32_bf16(aq, bk, acc, 0, 0, 0);
#pragma unroll
      for (int r = 0; r < 4; ++r)
        Ls[(quad * 4 + r) * LSP + jt * 16 + lam] = acc[r] * scale;
    }
  }
  __syncthreads();   // B2

  // ---- P2: CPB bias; wave owns 4 rows => 9 sub-iters of 64 pairs ----
  const f32x2 zero2 = {0.f, 0.f};
#pragma unroll 1
  for (int s = 0; s < 9; ++s) {
    int P = s * 64 + lane;
    int ii = P / 144, jj = P - ii * 144;
    int ig = i0 + w * 4 + ii;
    int iy = ig / 48, ix = ig - iy * 48;
    float p0 = (float)ix * (2.f / 47.f) - 1.f - sv0[jj];
    float p1 = (float)iy * (2.f / 47.f) - 1.f - sv1[jj];
    float s0f = copysignf(__logf(1.f + fabsf(p0)), p0);
    float s1f = copysignf(__logf(1.f + fabsf(p1)), p1);
    float bm[4];
#pragma unroll
    for (int mt = 0; mt < 4; ++mt) {
      float s0 = __shfl(s0f, mt * 16 + lam, 64);
      float s1 = __shfl(s1f, mt * 16 + lam, 64);
      f32x2 s0v = {s0, s0}, s1v = {s1, s1};
      union { uint u[4]; short8 s8; } cvt;
#pragma unroll
      for (int j = 0; j < 4; ++j) {
        f32x2 hv = __builtin_elementwise_max(
            __builtin_elementwise_fma(s0v, w00r2[j],
                __builtin_elementwise_fma(s1v, w01r2[j], b0r2[j])), zero2);
        cvt.u[j] = packbf(hv[1], hv[0]);
      }
      f32x4 dA = __builtin_amdgcn_mfma_f32_16x16x32_bf16(w1f0, cvt.s8, zA, 0, 0, 0);
      f32x4 dB = __builtin_amdgcn_mfma_f32_16x16x32_bf16(w1f1, cvt.s8, zB, 0, 0, 0);
      f32x2 a01 = __builtin_elementwise_max((f32x2){dA[0], dA[1]}, zero2);
      f32x2 a23 = __builtin_elementwise_max((f32x2){dA[2], dA[3]}, zero2);
      f32x2 c01 = __builtin_elementwise_max((f32x2){dB[0], dB[1]}, zero2);
      f32x2 c23 = __builtin_elementwise_max((f32x2){dB[2], dB[3]}, zero2);
      f32x2 av = __builtin_elementwise_fma(a01, w2A01,
                 __builtin_elementwise_fma(a23, w2A23,
                 __builtin_elementwise_fma(c01, w2B01,
                 __builtin_elementwise_fma(c23, w2B23, zero2))));
      float acc = av[0] + av[1];
      acc += __shfl_xor(acc, 16, 64);
      acc += __shfl_xor(acc, 32, 64);
      bm[mt] = acc;
    }
    float biasv = (quad == 0 ? bm[0] : quad == 1 ? bm[1] : quad == 2 ? bm[2] : bm[3]) + b2s;
    Ls[(w * 4 + ii) * LSP + jj] += biasv;
  }
  __syncthreads();   // B3

  // ---- P3: softmax per row (wave owns 4 rows); P packed bf16 in-place ----
#pragma unroll 1
  for (int rr = 0; rr < 4; ++rr) {
    int row = w * 4 + rr;
    const float* Lp = Ls + row * LSP;
    float l0 = Lp[lane], l1 = Lp[64 + lane];
    float l2 = (lane < 16) ? Lp[128 + lane] : -INFINITY;
    float m = fmaxf(fmaxf(l0, l1), l2);
#pragma unroll
    for (int k = 32; k >= 1; k >>= 1) m = fmaxf(m, __shfl_xor(m, k, 64));
    float e0 = __expf(l0 - m), e1 = __expf(l1 - m);
    float e2 = (lane < 16) ? __expf(l2 - m) : 0.f;
    float sum = e0 + e1 + e2;
#pragma unroll
    for (int k = 32; k >= 1; k >>= 1) sum += __shfl_xor(sum, k, 64);
    float inv = 1.f / sum;
    ushort* pb = (ushort*)(Lp + 64);
    pb[lane] = f2bf(e0 * inv);
    pb[64 + lane] = f2bf(e1 * inv);
    if (lane < 32) pb[128 + lane] = (lane < 16) ? f2bf(e2 * inv) : (ushort)0;
  }
  __syncthreads();   // B4

  // ---- P4: O = P·v (K=160, zero-padded); waves 0,1 take the 2 col-halves ----
  if (w < 2) {
    f32x4 o = {0.f, 0.f, 0.f, 0.f};
    const ushort* pb = (const ushort*)(Ls + lam * LSP + 64);
#pragma unroll
    for (int kb = 0; kb < 5; ++kb) {
      short8 ap = *(const short8*)(pb + kb * 32 + quad * 8);
      o = __builtin_amdgcn_mfma_f32_16x16x32_bf16(ap, vf[kb], o, 0, 0, 0);
    }
#pragma unroll
    for (int r = 0; r < 4; ++r) {
      int ig = i0 + quad * 4 + r;
      outh[((long)b * HWHW + ig) * 128 + g * 32 + w * 16 + lam] = f2bf(o[r]);
    }
  }
}

// grid (144 hw-chunks, 2 b, 2 oc-halves), 256 thr = 4 waves; wave owns 16 oc.
// MFMA out-proj, zero LDS: A-frags straight from bf16 outh; B-frags from fp32
// wo with inline v_perm pack.
__global__ __launch_bounds__(256) void out_kernel(
    const ushort* __restrict__ outh, const float* __restrict__ wo,
    const float* __restrict__ bo, const float* __restrict__ x,
    const float* __restrict__ gamma, float* __restrict__ out) {
  int b = blockIdx.y;
  int hw0 = blockIdx.x * 16;
  int oc0 = blockIdx.z * 64;
  int t = threadIdx.x;
  int w = t >> 6, lane = t & 63, lam = lane & 15, quad = lane >> 4;
  const ushort* abase = outh + ((long)b * HWHW + hw0 + lam) * 128 + quad * 8;
  const float* wb0 = wo + (oc0 + w * 16 + lam) * 128 + quad * 8;
  f32x4 acc0 = {0.f, 0.f, 0.f, 0.f};
#pragma unroll
  for (int ks = 0; ks < 4; ++ks) {
    short8 a = *(const short8*)(abase + ks * 32);
    float4 wa = *(const float4*)(wb0 + ks * 32);
    float4 wb = *(const float4*)(wb0 + ks * 32 + 4);
    union { uint u[4]; short8 s8; } p0;
    p0.u[0] = packbf(wa.y, wa.x); p0.u[1] = packbf(wa.w, wa.z);
    p0.u[2] = packbf(wb.y, wb.x); p0.u[3] = packbf(wb.w, wb.z);
    acc0 = __builtin_amdgcn_mfma_f32_16x16x32_bf16(a, p0.s8, acc0, 0, 0, 0);
  }
  float gm = gamma[0];
  float* out0 = out;
  float* out1 = out + 2 * 128 * HWHW;
  {
    int oc = oc0 + w * 16 + lam;
    float bv = bo[oc];
    long base = ((long)(b * 128 + oc)) * HWHW + hw0 + quad * 4;
    float4 xv = *(const float4*)(x + base);
    float4 a1, a0;
    a1.x = acc0[0] + bv; a1.y = acc0[1] + bv; a1.z = acc0[2] + bv; a1.w = acc0[3] + bv;
    a0.x = fmaf(gm, a1.x, xv.x); a0.y = fmaf(gm, a1.y, xv.y);
    a0.z = fmaf(gm, a1.z, xv.z); a0.w = fmaf(gm, a1.w, xv.w);
    *(float4*)(out1 + base) = a1;
    *(float4*)(out0 + base) = a0;
  }
}

extern "C" void kernel_launch(void* const* d_in, const int* in_sizes, int n_in,
                              void* d_out, int out_size, void* d_ws, size_t ws_size,
                              hipStream_t stream) {
  const float* x     = (const float*)d_in[0];
  const float* gamma = (const float*)d_in[1];
  const float* wq    = (const float*)d_in[2];
  const float* wk    = (const float*)d_in[3];
  const float* wv    = (const float*)d_in[4];
  const float* wo    = (const float*)d_in[5];
  const float* bo    = (const float*)d_in[6];
  const float* wdw   = (const float*)d_in[7];
  const float* bdw   = (const float*)d_in[8];
  const float* wproj = (const float*)d_in[9];
  const float* cw0   = (const float*)d_in[10];
  const float* cb0   = (const float*)d_in[11];
  const float* cw1   = (const float*)d_in[12];
  const float* cb1   = (const float*)d_in[13];
  const float* cw2   = (const float*)d_in[14];
  const float* cb2   = (const float*)d_in[15];
  char* wsb = (char*)d_ws;
  float* vn0  = (float*)wsb;
  float* vn1  = (float*)(wsb + 4608);
  ushort* ktb = (ushort*)(wsb + 9216);
  ushort* vtb = (ushort*)(wsb + 82944);
  ushort* outh = (ushort*)(wsb + 164864);
  float* out  = (float*)d_out;

  offset_kv_kernel<<<dim3(12, 8), 384, 0, stream>>>(x, wq, wdw, bdw, wproj, wk, wv,
                                                    vn0, vn1, ktb, vtb);
  attn_fused_kernel<<<dim3(144, 8), 256, 0, stream>>>(x, wq, ktb, vtb, vn0, vn1,
                                                      cw0, cb0, cw1, cb1, cw2, cb2, outh);
  out_kernel<<<dim3(144, 2, 2), 256, 0, stream>>>(outh, wo, bo, x, gamma, out);
}

// Round 10
// 129.504 us; speedup vs baseline: 1.0301x; 1.0301x over previous
//
#include <hip/hip_runtime.h>
#include <math.h>

// dims
#define HWHW 2304   // 48*48
#define JD   144    // 12*12
#define LSP  148    // Ls row stride in dwords

typedef __attribute__((ext_vector_type(8))) short short8;
typedef __attribute__((ext_vector_type(4))) float f32x4;
typedef __attribute__((ext_vector_type(2))) float f32x2;

__device__ inline ushort f2bf(float f) {
  uint u = __float_as_uint(f);
  u += 0x7fffu + ((u >> 16) & 1u);   // RNE
  return (ushort)(u >> 16);
}
__device__ inline float bf2f(ushort s) { return __uint_as_float((uint)s << 16); }
__device__ inline uint packbf(float hi, float lo) {   // truncating {hi16(hi),hi16(lo)}
  return __builtin_amdgcn_perm(__float_as_uint(hi), __float_as_uint(lo), 0x07060302);
}

// ws layout (byte offsets)
// vn0     [8][144] f32       @ 0
// vn1     [8][144] f32       @ 4608
// kt_bf   [8][144][32] u16   @ 9216    (73728 B)
// vtT_bf  [8][32][160] u16   @ 82944   (81920 B, j=144..159 zeroed)
// outh_bf [2][2304][128] u16 @ 164864  (1179648 B, end 1344512 B)

// grid (12 hd, 8 bg), 384 thr = 6 waves. Fused: q=Wq·x via MFMA (wave w owns
// conv input row ry=w) -> depthwise conv -> GELU -> proj -> tanh -> grid coords
// -> bilinear sample -> k/v proj (bf16 out).
__global__ __launch_bounds__(384) void offset_kv_kernel(
    const float* __restrict__ x, const float* __restrict__ wq,
    const float* __restrict__ wdw, const float* __restrict__ bdw,
    const float* __restrict__ wproj, const float* __restrict__ wk,
    const float* __restrict__ wv,
    float* __restrict__ vn0, float* __restrict__ vn1,
    ushort* __restrict__ ktb, ushort* __restrict__ vtb) {
  __shared__ float qs[288][33];      // [ry*48+col][c], +1 pad
  __shared__ float wdws[36][32];     // [k][c]
  __shared__ float wkl[32][33], wvl[32][33];   // [d][c]
  __shared__ float kvs[32][13];      // [c][j] (+pad)
  __shared__ float spx[12], spy[12];
  int hd = blockIdx.x, bg = blockIdx.y, b = bg >> 2, g = bg & 3;
  int t = threadIdx.x;
  int w = t >> 6, lane = t & 63, lam = lane & 15, quad = lane >> 4;

  // ---- q-tile via MFMA: wave w computes conv-input row ry=w (hy=hd*4-1+w) ----
  {
    int hy = hd * 4 - 1 + w;
    if (hy >= 0 && hy < 48) {
      // B-frags of Wq^T (shared by the wave's 3 tiles)
      const float* wqg = wq + (g * 32) * 32;
      float4 wa = *(const float4*)(wqg + lam * 32 + quad * 8);
      float4 wb = *(const float4*)(wqg + lam * 32 + quad * 8 + 4);
      float4 wc = *(const float4*)(wqg + (16 + lam) * 32 + quad * 8);
      float4 wd = *(const float4*)(wqg + (16 + lam) * 32 + quad * 8 + 4);
      union { uint u[4]; short8 s8; } bf0, bf1;
      bf0.u[0] = packbf(wa.y, wa.x); bf0.u[1] = packbf(wa.w, wa.z);
      bf0.u[2] = packbf(wb.y, wb.x); bf0.u[3] = packbf(wb.w, wb.z);
      bf1.u[0] = packbf(wc.y, wc.x); bf1.u[1] = packbf(wc.w, wc.z);
      bf1.u[2] = packbf(wd.y, wd.x); bf1.u[3] = packbf(wd.w, wd.z);
      const float* xg = x + (b * 128 + g * 32) * HWHW + hy * 48;
#pragma unroll
      for (int tt = 0; tt < 3; ++tt) {
        int col = tt * 16 + lam;
        union { uint u[4]; short8 s8; } xa;
#pragma unroll
        for (int j = 0; j < 4; ++j) {
          float x0 = xg[(quad * 8 + 2 * j) * HWHW + col];
          float x1 = xg[(quad * 8 + 2 * j + 1) * HWHW + col];
          xa.u[j] = packbf(x1, x0);
        }
        f32x4 z = {0.f, 0.f, 0.f, 0.f};
        f32x4 d0 = __builtin_amdgcn_mfma_f32_16x16x32_bf16(xa.s8, bf0.s8, z, 0, 0, 0);
        f32x4 d1 = __builtin_amdgcn_mfma_f32_16x16x32_bf16(xa.s8, bf1.s8, z, 0, 0, 0);
        int p = w * 48 + tt * 16 + quad * 4;
#pragma unroll
        for (int r = 0; r < 4; ++r) {
          qs[p + r][lam] = d0[r];
          qs[p + r][16 + lam] = d1[r];
        }
      }
    } else {
#pragma unroll
      for (int tt = 0; tt < 3; ++tt) {
        int p = w * 48 + tt * 16 + quad * 4;
#pragma unroll
        for (int r = 0; r < 4; ++r) {
          qs[p + r][lam] = 0.f;
          qs[p + r][16 + lam] = 0.f;
        }
      }
    }
  }
  for (int u = t; u < 1152; u += 384) wdws[u >> 5][u & 31] = wdw[(u & 31) * 36 + (u >> 5)];
  for (int u = t; u < 1024; u += 384) {
    int d = u >> 5, c = u & 31;
    wkl[d][c] = wk[g * 1024 + u];
    wvl[d][c] = wv[g * 1024 + u];
  }
  __syncthreads();
  {
    int wd = t >> 5, c = t & 31;
    float s = 0.f;
#pragma unroll
    for (int ky = 0; ky < 6; ++ky) {
#pragma unroll
      for (int kx = 0; kx < 6; ++kx) {
        int wx = wd * 4 - 1 + kx;
        if (wx >= 0 && wx < 48)
          s += wdws[ky * 6 + kx][c] * qs[ky * 48 + wx][c];
      }
    }
    s += bdw[c];
    s = 0.5f * s * (1.f + erff(s * 0.70710678118654752f));  // exact GELU
    float g0 = wproj[c] * s;
    float g1 = wproj[32 + c] * s;
#pragma unroll
    for (int k = 16; k >= 1; k >>= 1) {
      g0 += __shfl_xor(g0, k, 64);
      g1 += __shfl_xor(g1, k, 64);
    }
    if (c == 0) {
      float off0 = tanhf(g0) * 4.f;
      float off1 = tanhf(g1) * 4.f;
      float n0 = 2.f * ((float)wd + off0) / 11.f - 1.f;
      float n1 = 2.f * ((float)hd + off1) / 11.f - 1.f;
      int idx = bg * JD + hd * 12 + wd;
      vn0[idx] = n0;
      vn1[idx] = n1;
      spx[wd] = ((n0 + 1.f) * 48.f - 1.f) * 0.5f;
      spy[wd] = ((n1 + 1.f) * 48.f - 1.f) * 0.5f;
    }
  }
  __syncthreads();
  {
    int j = t >> 5, c = t & 31;
    float fx = spx[j], fy = spy[j];
    float x0 = floorf(fx), y0 = floorf(fy);
    float wx = fx - x0, wy = fy - y0;
    int xi = (int)x0, yi = (int)y0;
    const float* xp = x + (b * 128 + g * 32 + c) * HWHW;
    float v00 = 0.f, v10 = 0.f, v01 = 0.f, v11 = 0.f;
    bool okx0 = (xi >= 0) & (xi < 48), okx1 = (xi + 1 >= 0) & (xi + 1 < 48);
    if (yi >= 0 && yi < 48) {
      if (okx0) v00 = xp[yi * 48 + xi];
      if (okx1) v10 = xp[yi * 48 + xi + 1];
    }
    if (yi + 1 >= 0 && yi + 1 < 48) {
      if (okx0) v01 = xp[(yi + 1) * 48 + xi];
      if (okx1) v11 = xp[(yi + 1) * 48 + xi + 1];
    }
    kvs[c][j] = v00 * (1.f - wx) * (1.f - wy) + v10 * wx * (1.f - wy)
              + v01 * (1.f - wx) * wy + v11 * wx * wy;
  }
  __syncthreads();
  {
    int j = t >> 5, d = t & 31;
    float ak = 0.f, av = 0.f;
#pragma unroll
    for (int c = 0; c < 32; ++c) {
      float val = kvs[c][j];
      ak += wkl[d][c] * val;
      av += wvl[d][c] * val;
    }
    int jg = hd * 12 + j;
    ktb[bg * 4608 + jg * 32 + d] = f2bf(ak);
    vtb[bg * 5120 + d * 160 + jg] = f2bf(av);
  }
  if (hd == 0) {   // zero the v K-pad for this bg (j = 144..159)
    for (int u = t; u < 512; u += 384)
      vtb[bg * 5120 + (u >> 4) * 160 + 144 + (u & 15)] = 0;
  }
}

// Fused attention: block = (bg, 16 q-rows), 256 thr = 4 waves.
// q inline via MFMA; k/v straight from global; P2 bias MLP reads per-pair
// (s0,s1) from a precomputed LDS table (affine addressing, no shfl/div/log in
// the hot loop); P3 softmax processes the wave's 4 rows in parallel (quad=row).
__global__ __launch_bounds__(256) void attn_fused_kernel(
    const float* __restrict__ x, const float* __restrict__ wq,
    const ushort* __restrict__ ktb, const ushort* __restrict__ vtb,
    const float* __restrict__ vn0, const float* __restrict__ vn1,
    const float* __restrict__ w0, const float* __restrict__ b0,
    const float* __restrict__ w1, const float* __restrict__ b1,
    const float* __restrict__ w2, const float* __restrict__ b2,
    ushort* __restrict__ outh) {
  __shared__ __align__(16) char smem[30080];
  float* Ls = (float*)smem;                    // [16][LSP] fp32; P bf16 at dwords 64..143
  f32x2* st = (f32x2*)(smem + 9472);           // [2304] {s0,s1} per (row,j) pair
  ushort* qbf = (ushort*)(smem + 27904);       // [16][32] bf16
  float* sv0 = (float*)(smem + 28928);         // [144]
  float* sv1 = (float*)(smem + 29504);         // [144]

  int bg = blockIdx.y, b = bg >> 2, g = bg & 3;
  int i0 = blockIdx.x * 16;
  int t = threadIdx.x;
  int w = t >> 6, lane = t & 63;
  int lam = lane & 15, quad = lane >> 4;

  if (t < JD) { sv0[t] = vn0[bg * JD + t]; sv1[t] = vn1[bg * JD + t]; }

  // ---- q-tile via MFMA: D = X[16 rows][32c] · Wq^T -> C-layout -> LDS ----
  {
    const float* wqg = wq + (g * 32) * 32;
    float4 wa = *(const float4*)(wqg + lam * 32 + quad * 8);
    float4 wb = *(const float4*)(wqg + lam * 32 + quad * 8 + 4);
    float4 wc = *(const float4*)(wqg + (16 + lam) * 32 + quad * 8);
    float4 wd = *(const float4*)(wqg + (16 + lam) * 32 + quad * 8 + 4);
    union { uint u[4]; short8 s8; } bf0, bf1, xa;
    bf0.u[0] = packbf(wa.y, wa.x); bf0.u[1] = packbf(wa.w, wa.z);
    bf0.u[2] = packbf(wb.y, wb.x); bf0.u[3] = packbf(wb.w, wb.z);
    bf1.u[0] = packbf(wc.y, wc.x); bf1.u[1] = packbf(wc.w, wc.z);
    bf1.u[2] = packbf(wd.y, wd.x); bf1.u[3] = packbf(wd.w, wd.z);
    const float* xg = x + (b * 128 + g * 32) * HWHW + i0;
#pragma unroll
    for (int j = 0; j < 4; ++j) {
      float x0 = xg[(quad * 8 + 2 * j) * HWHW + lam];
      float x1 = xg[(quad * 8 + 2 * j + 1) * HWHW + lam];
      xa.u[j] = packbf(x1, x0);
    }
    f32x4 z = {0.f, 0.f, 0.f, 0.f};
    f32x4 d0 = __builtin_amdgcn_mfma_f32_16x16x32_bf16(xa.s8, bf0.s8, z, 0, 0, 0);
    f32x4 d1 = __builtin_amdgcn_mfma_f32_16x16x32_bf16(xa.s8, bf1.s8, z, 0, 0, 0);
#pragma unroll
    for (int r = 0; r < 4; ++r) {
      qbf[(quad * 4 + r) * 32 + lam] = f2bf(d0[r]);
      qbf[(quad * 4 + r) * 32 + 16 + lam] = f2bf(d1[r]);
    }
  }

  // ---- per-lane resident weights (float2-packed for v_pk_fma_f32) ----
  f32x2 w00r2[4], w01r2[4], b0r2[4];
#pragma unroll
  for (int j = 0; j < 4; ++j) {
    int k = quad * 8 + 2 * j;
    w00r2[j] = (f32x2){w0[k], w0[k + 1]};
    w01r2[j] = (f32x2){w0[32 + k], w0[32 + k + 1]};
    b0r2[j]  = (f32x2){b0[k], b0[k + 1]};
  }
  short8 w1f0, w1f1;   // W1^T A-frags (m=n-out, k=c-in), two 16-row tiles
#pragma unroll
  for (int j = 0; j < 8; ++j) {
    int k = quad * 8 + j;
    w1f0[j] = (short)f2bf(w1[k * 32 + lam]);
    w1f1[j] = (short)f2bf(w1[k * 32 + 16 + lam]);
  }
  f32x4 zA, zB;       // b1 folded into C-init (n = quad*4+r / 16+quad*4+r)
  f32x2 w2A01, w2A23, w2B01, w2B23;
#pragma unroll
  for (int r = 0; r < 4; ++r) {
    zA[r] = b1[quad * 4 + r];
    zB[r] = b1[16 + quad * 4 + r];
  }
  w2A01 = (f32x2){w2[quad * 4], w2[quad * 4 + 1]};
  w2A23 = (f32x2){w2[quad * 4 + 2], w2[quad * 4 + 3]};
  w2B01 = (f32x2){w2[16 + quad * 4], w2[16 + quad * 4 + 1]};
  w2B23 = (f32x2){w2[16 + quad * 4 + 2], w2[16 + quad * 4 + 3]};
  float b2s = b2[0];

  // ---- prefetch v-frags for P4 (waves 0,1) ----
  short8 vf[5];
  if (w < 2) {
    const ushort* vb = vtb + bg * 5120 + (w * 16 + lam) * 160;
#pragma unroll
    for (int kb = 0; kb < 5; ++kb)
      vf[kb] = *(const short8*)(vb + kb * 32 + quad * 8);
  }

  __syncthreads();   // B0: qbf + sv ready

  // ---- P1: sim = q·kT (scaled); k straight from global ----
  const float scale = 0.17677669529663687f;   // 32^-0.5
  {
    short8 aq = *(const short8*)(qbf + lam * 32 + quad * 8);
    const ushort* kb = ktb + bg * 4608;
#pragma unroll 1
    for (int jt = w; jt < 9; jt += 4) {
      short8 bk = *(const short8*)(kb + (jt * 16 + lam) * 32 + quad * 8);
      f32x4 acc = {0.f, 0.f, 0.f, 0.f};
      acc = __builtin_amdgcn_mfma_f32_16x16x32_bf16(aq, bk, acc, 0, 0, 0);
#pragma unroll
      for (int r = 0; r < 4; ++r)
        Ls[(quad * 4 + r) * LSP + jt * 16 + lam] = acc[r] * scale;
    }
  }

  // ---- build (s0,s1) table: block has single iy (48%16==0), 16 ix values ----
  {
    int iy = i0 / 48;
    int ix0 = i0 - iy * 48;
    float qn1 = (float)iy * (2.f / 47.f) - 1.f;
#pragma unroll 1
    for (int u = t; u < 2304; u += 256) {
      int r = u / 144, jj = u - r * 144;
      float qn0 = (float)(ix0 + r) * (2.f / 47.f) - 1.f;
      float p0 = qn0 - sv0[jj];
      float p1 = qn1 - sv1[jj];
      st[u] = (f32x2){copysignf(__logf(1.f + fabsf(p0)), p0),
                      copysignf(__logf(1.f + fabsf(p1)), p1)};
    }
  }
  __syncthreads();   // B2: Ls(sim) + st ready

  // ---- P2: CPB bias; wave owns 4 rows => 9 sub-iters of 64 pairs ----
  const f32x2 zero2 = {0.f, 0.f};
  int pbase = w * 576;
#pragma unroll 1
  for (int s = 0; s < 9; ++s) {
    float bm[4];
#pragma unroll
    for (int mt = 0; mt < 4; ++mt) {
      f32x2 sv = st[pbase + s * 64 + mt * 16 + lam];   // broadcast across quad
      f32x2 s0v = {sv[0], sv[0]}, s1v = {sv[1], sv[1]};
      union { uint u[4]; short8 s8; } cvt;
#pragma unroll
      for (int j = 0; j < 4; ++j) {
        f32x2 hv = __builtin_elementwise_max(
            __builtin_elementwise_fma(s0v, w00r2[j],
                __builtin_elementwise_fma(s1v, w01r2[j], b0r2[j])), zero2);
        cvt.u[j] = packbf(hv[1], hv[0]);
      }
      f32x4 dA = __builtin_amdgcn_mfma_f32_16x16x32_bf16(w1f0, cvt.s8, zA, 0, 0, 0);
      f32x4 dB = __builtin_amdgcn_mfma_f32_16x16x32_bf16(w1f1, cvt.s8, zB, 0, 0, 0);
      f32x2 a01 = __builtin_elementwise_max((f32x2){dA[0], dA[1]}, zero2);
      f32x2 a23 = __builtin_elementwise_max((f32x2){dA[2], dA[3]}, zero2);
      f32x2 c01 = __builtin_elementwise_max((f32x2){dB[0], dB[1]}, zero2);
      f32x2 c23 = __builtin_elementwise_max((f32x2){dB[2], dB[3]}, zero2);
      f32x2 av = __builtin_elementwise_fma(a01, w2A01,
                 __builtin_elementwise_fma(a23, w2A23,
                 __builtin_elementwise_fma(c01, w2B01,
                 __builtin_elementwise_fma(c23, w2B23, zero2))));
      float acc = av[0] + av[1];
      acc += __shfl_xor(acc, 16, 64);
      acc += __shfl_xor(acc, 32, 64);
      bm[mt] = acc;
    }
    int P = s * 64 + lane;
    int ii = P / 144, jj = P - ii * 144;
    float biasv = (quad == 0 ? bm[0] : quad == 1 ? bm[1] : quad == 2 ? bm[2] : bm[3]) + b2s;
    Ls[(w * 4 + ii) * LSP + jj] += biasv;
  }
  __syncthreads();   // B3

  // ---- P3: softmax, wave's 4 rows in parallel (quad = row, 16 lanes/row) ----
  {
    int row = w * 4 + quad;
    float* Lp = Ls + row * LSP;
    float lv[9];
#pragma unroll
    for (int k = 0; k < 9; ++k) lv[k] = Lp[lam + 16 * k];
    float m = lv[0];
#pragma unroll
    for (int k = 1; k < 9; ++k) m = fmaxf(m, lv[k]);
#pragma unroll
    for (int k = 8; k >= 1; k >>= 1) m = fmaxf(m, __shfl_xor(m, k, 64));
    float e[9], sum = 0.f;
#pragma unroll
    for (int k = 0; k < 9; ++k) { e[k] = __expf(lv[k] - m); sum += e[k]; }
#pragma unroll
    for (int k = 8; k >= 1; k >>= 1) sum += __shfl_xor(sum, k, 64);
    float inv = 1.f / sum;
    ushort* pb = (ushort*)(Lp + 64);
#pragma unroll
    for (int k = 0; k < 9; ++k) pb[lam + 16 * k] = f2bf(e[k] * inv);
    pb[144 + lam] = 0;   // K-pad for P4
  }
  __syncthreads();   // B4

  // ---- P4: O = P·v (K=160, zero-padded); waves 0,1 take the 2 col-halves ----
  if (w < 2) {
    f32x4 o = {0.f, 0.f, 0.f, 0.f};
    const ushort* pb = (const ushort*)(Ls + lam * LSP + 64);
#pragma unroll
    for (int kb = 0; kb < 5; ++kb) {
      short8 ap = *(const short8*)(pb + kb * 32 + quad * 8);
      o = __builtin_amdgcn_mfma_f32_16x16x32_bf16(ap, vf[kb], o, 0, 0, 0);
    }
#pragma unroll
    for (int r = 0; r < 4; ++r) {
      int ig = i0 + quad * 4 + r;
      outh[((long)b * HWHW + ig) * 128 + g * 32 + w * 16 + lam] = f2bf(o[r]);
    }
  }
}

// grid (144 hw-chunks, 2 b, 2 oc-halves), 256 thr = 4 waves; wave owns 16 oc.
// MFMA out-proj, zero LDS: A-frags straight from bf16 outh; B-frags from fp32
// wo with inline v_perm pack.
__global__ __launch_bounds__(256) void out_kernel(
    const ushort* __restrict__ outh, const float* __restrict__ wo,
    const float* __restrict__ bo, const float* __restrict__ x,
    const float* __restrict__ gamma, float* __restrict__ out) {
  int b = blockIdx.y;
  int hw0 = blockIdx.x * 16;
  int oc0 = blockIdx.z * 64;
  int t = threadIdx.x;
  int w = t >> 6, lane = t & 63, lam = lane & 15, quad = lane >> 4;
  const ushort* abase = outh + ((long)b * HWHW + hw0 + lam) * 128 + quad * 8;
  const float* wb0 = wo + (oc0 + w * 16 + lam) * 128 + quad * 8;
  f32x4 acc0 = {0.f, 0.f, 0.f, 0.f};
#pragma unroll
  for (int ks = 0; ks < 4; ++ks) {
    short8 a = *(const short8*)(abase + ks * 32);
    float4 wa = *(const float4*)(wb0 + ks * 32);
    float4 wb = *(const float4*)(wb0 + ks * 32 + 4);
    union { uint u[4]; short8 s8; } p0;
    p0.u[0] = packbf(wa.y, wa.x); p0.u[1] = packbf(wa.w, wa.z);
    p0.u[2] = packbf(wb.y, wb.x); p0.u[3] = packbf(wb.w, wb.z);
    acc0 = __builtin_amdgcn_mfma_f32_16x16x32_bf16(a, p0.s8, acc0, 0, 0, 0);
  }
  float gm = gamma[0];
  float* out0 = out;
  float* out1 = out + 2 * 128 * HWHW;
  {
    int oc = oc0 + w * 16 + lam;
    float bv = bo[oc];
    long base = ((long)(b * 128 + oc)) * HWHW + hw0 + quad * 4;
    float4 xv = *(const float4*)(x + base);
    float4 a1, a0;
    a1.x = acc0[0] + bv; a1.y = acc0[1] + bv; a1.z = acc0[2] + bv; a1.w = acc0[3] + bv;
    a0.x = fmaf(gm, a1.x, xv.x); a0.y = fmaf(gm, a1.y, xv.y);
    a0.z = fmaf(gm, a1.z, xv.z); a0.w = fmaf(gm, a1.w, xv.w);
    *(float4*)(out1 + base) = a1;
    *(float4*)(out0 + base) = a0;
  }
}

extern "C" void kernel_launch(void* const* d_in, const int* in_sizes, int n_in,
                              void* d_out, int out_size, void* d_ws, size_t ws_size,
                              hipStream_t stream) {
  const float* x     = (const float*)d_in[0];
  const float* gamma = (const float*)d_in[1];
  const float* wq    = (const float*)d_in[2];
  const float* wk    = (const float*)d_in[3];
  const float* wv    = (const float*)d_in[4];
  const float* wo    = (const float*)d_in[5];
  const float* bo    = (const float*)d_in[6];
  const float* wdw   = (const float*)d_in[7];
  const float* bdw   = (const float*)d_in[8];
  const float* wproj = (const float*)d_in[9];
  const float* cw0   = (const float*)d_in[10];
  const float* cb0   = (const float*)d_in[11];
  const float* cw1   = (const float*)d_in[12];
  const float* cb1   = (const float*)d_in[13];
  const float* cw2   = (const float*)d_in[14];
  const float* cb2   = (const float*)d_in[15];
  char* wsb = (char*)d_ws;
  float* vn0  = (float*)wsb;
  float* vn1  = (float*)(wsb + 4608);
  ushort* ktb = (ushort*)(wsb + 9216);
  ushort* vtb = (ushort*)(wsb + 82944);
  ushort* outh = (ushort*)(wsb + 164864);
  float* out  = (float*)d_out;

  offset_kv_kernel<<<dim3(12, 8), 384, 0, stream>>>(x, wq, wdw, bdw, wproj, wk, wv,
                                                    vn0, vn1, ktb, vtb);
  attn_fused_kernel<<<dim3(144, 8), 256, 0, stream>>>(x, wq, ktb, vtb, vn0, vn1,
                                                      cw0, cb0, cw1, cb1, cw2, cb2, outh);
  out_kernel<<<dim3(144, 2, 2), 256, 0, stream>>>(outh, wo, bo, x, gamma, out);
}